// Round 8
// baseline (226.611 us; speedup 1.0000x reference)
//
#include <hip/hip_runtime.h>
#include <hip/hip_bf16.h>
#include <math.h>

// VectorQuantizer: z [8,256,32,32] f32, codebook [8192,256] f32
// outputs (flat f32): z_q [2097152] NCHW, idx [8192] (as float), loss, perplexity
#define KC 8192
#define DD 256
#define NP 8192
#define ZQ_ELEMS 2097152
#define MARGIN_S 2.5e-4f   // s-space (== 5e-4 in d-space, validated rounds 4-7)
#define NPART 32           // code-group partials (gemm grid.y)

// ws layout (bytes)
#define OFF_ABIG 0u           // bf16 [8192][512]  (Zh | Zl)  points
#define OFF_BBIG 8388608u     // bf16 [8192][512]  (Wh | Wl)  codes
#define OFF_NRM  16777216u    // f32 [8192]
#define OFF_WSQ  16809984u    // f32 [8192]
#define OFF_PV1  16875520u    // f32 [32][8192]
#define OFF_PV2  17924096u    // f32 [32][8192]
#define OFF_PK1  18972672u    // i32 [32][8192]
#define OFF_LOSSP 20021248u   // f64 [512]
#define OFF_HIST 20090880u    // i32 [8192]
#define OFF_PACK 20123648u    // u64 [8192]
#define OFF_LIST 20189184u    // i32 [8192]
#define OFF_NFLG 20221952u    // i32 [1]

typedef __attribute__((ext_vector_type(8))) short bf16x8;
typedef __attribute__((ext_vector_type(16))) float f32x16;
typedef __attribute__((address_space(3))) void as3_void;
typedef const __attribute__((address_space(1))) void as1_cvoid;

#define GLOAD16(g, l) __builtin_amdgcn_global_load_lds((as1_cvoid*)(g), (as3_void*)(l), 16, 0, 0)

__device__ inline double waveReduceD(double v) {
#pragma unroll
    for (int off = 32; off; off >>= 1) v += __shfl_down(v, off, 64);
    return v;
}

static __device__ inline unsigned short f2bf(float f) {
    __hip_bfloat16 h = __float2bfloat16(f);  // RNE
    return *(unsigned short*)&h;
}
static __device__ inline float bf2f(unsigned short u) {
    unsigned v = ((unsigned)u) << 16;
    float f;
    __builtin_memcpy(&f, &v, 4);
    return f;
}

// fused prep: blocks 0..8191 codebook rows (normalize + split + wsq/nrm +
// zero hist/nflag); blocks 8192..16383 z points (split + transpose only).
__global__ __launch_bounds__(256) void prep(
    const float* __restrict__ cb, const float* __restrict__ z,
    unsigned short* __restrict__ Bbig, unsigned short* __restrict__ Abig,
    float* __restrict__ nrm, float* __restrict__ wsq,
    int* __restrict__ hist, int* __restrict__ nflag) {
    __shared__ double lred[4];
    __shared__ float mh;
    int bid = blockIdx.x, t = threadIdx.x;
    int lane = t & 63, wid = t >> 6;
    if (bid < KC) {
        int k = bid;
        if (k < 32) hist[k * 256 + t] = 0;
        if (k == 32 && t == 0) *nflag = 0;
        float c = cb[k * DD + t];
        double s = waveReduceD((double)c * (double)c);
        if (lane == 0) lred[wid] = s;
        __syncthreads();
        if (t == 0) {
            double tot = lred[0] + lred[1] + lred[2] + lred[3];
            float nf = sqrtf((float)tot);
            mh = fmaxf(nf, 1e-12f);
            nrm[k] = mh;
            wsq[k] = (float)(tot / ((double)mh * (double)mh));
        }
        __syncthreads();
        float wv = c / mh;
        unsigned short hi = f2bf(wv);
        unsigned short lo = f2bf(wv - bf2f(hi));
        Bbig[k * 512 + t] = hi;
        Bbig[k * 512 + 256 + t] = lo;
    } else {
        int n = bid - KC;
        int b = n >> 10, hw = n & 1023;
        float v = z[(b * DD + t) * 1024 + hw];
        unsigned short hi = f2bf(v);
        unsigned short lo = f2bf(v - bf2f(hi));
        Abig[n * 512 + t] = hi;
        Abig[n * 512 + 256 + t] = lo;
    }
}

// Deep-pipelined MFMA GEMM (R6 schedule) on 32x32x16 bf16 + top-2 screen.
// C[256 codes][256 points] per block; A = W (codes), B = Z (points).
// Quad-buffered LDS, stage depth 3, counted vmcnt(8), 1 barrier/K-tile.
// acc init = -wsq/2  =>  score dv = -acc = wsq/2 - dot (argmin == argmin d).
// Swizzle f(r) = ((r>>1)^(r>>3))&3 on 16B chunks; inverse on global source,
// forward on ds_read; gload dest linear (rule #21).
__global__ __launch_bounds__(512, 2) void gemm_top2(
    const unsigned short* __restrict__ Abig, const unsigned short* __restrict__ Bbig,
    const float* __restrict__ wsq,
    float* __restrict__ pv1, float* __restrict__ pv2, int* __restrict__ pk1) {
    // [buf 0..3][ W 256x32 (8192 sh) | Z 256x32 (8192 sh) ] = 128 KiB
    __shared__ unsigned short sAB[65536];

    int t = threadIdx.x;
    int l = t & 63, w = t >> 6;
    int wm = w >> 2, wn = w & 3;
    int l31 = l & 31, lhi = l >> 5;
    int kc0 = blockIdx.y * 256;   // code base (C rows)
    int n0 = blockIdx.x * 256;    // point base (C cols)

    // staging geometry
    int row0 = t >> 2;                                    // piece-local row 0..127
    int fr = ((row0 >> 1) ^ (row0 >> 3)) & 3;             // f() invariant to +32/+128
    int kk = (((t & 3) ^ fr) << 3);                       // inverse-swz src chunk (shorts)
    int flr = ((l31 >> 1) ^ (l31 >> 3)) & 3;              // read-side f(row)

#define STAGE4(kt_) do {                                                       \
    int p_ = (kt_) >> 3;                                                       \
    int zo_ = (p_ == 2 ? 256 : 0) + ((kt_) & 7) * 32;                          \
    int wo_ = (p_ == 1 ? 256 : 0) + ((kt_) & 7) * 32;                          \
    int b_ = ((kt_) & 3) * 16384;                                              \
    GLOAD16(Bbig + (size_t)(kc0 + row0) * 512 + wo_ + kk, &sAB[b_ + t * 8]);   \
    GLOAD16(Bbig + (size_t)(kc0 + row0 + 128) * 512 + wo_ + kk, &sAB[b_ + 4096 + t * 8]); \
    GLOAD16(Abig + (size_t)(n0 + row0) * 512 + zo_ + kk, &sAB[b_ + 8192 + t * 8]); \
    GLOAD16(Abig + (size_t)(n0 + row0 + 128) * 512 + zo_ + kk, &sAB[b_ + 12288 + t * 8]); \
} while (0)

    // accumulators: 4 m-tiles (codes) x 2 n-tiles (points), 32x32 each
    f32x16 acc[4][2];
#pragma unroll
    for (int mt = 0; mt < 4; ++mt) {
#pragma unroll
        for (int r = 0; r < 16; ++r) {
            float hv = -0.5f * wsq[kc0 + wm * 128 + mt * 32 + (r & 3) + 8 * (r >> 2) + 4 * lhi];
            acc[mt][0][r] = hv;
            acc[mt][1][r] = hv;
        }
    }

    // read offsets (shorts) for k-slot 0/1: logical chunk c = s*2 + lhi
    int aoff0 = (((0 + lhi) ^ flr) << 3);
    int aoff1 = (((2 + lhi) ^ flr) << 3);

#define KBODY(bb_) do {                                                        \
    bf16x8 a0_[4], a1_[4], b0_[2], b1_[2];                                     \
    _Pragma("unroll")                                                          \
    for (int mt = 0; mt < 4; ++mt) {                                           \
        int rb_ = (bb_) + (wm * 128 + mt * 32 + l31) * 32;                     \
        a0_[mt] = *(const bf16x8*)&sAB[rb_ + aoff0];                           \
        a1_[mt] = *(const bf16x8*)&sAB[rb_ + aoff1];                           \
    }                                                                          \
    _Pragma("unroll")                                                          \
    for (int nt = 0; nt < 2; ++nt) {                                           \
        int rb_ = (bb_) + 8192 + (wn * 64 + nt * 32 + l31) * 32;               \
        b0_[nt] = *(const bf16x8*)&sAB[rb_ + aoff0];                           \
        b1_[nt] = *(const bf16x8*)&sAB[rb_ + aoff1];                           \
    }                                                                          \
    __builtin_amdgcn_s_setprio(1);                                             \
    _Pragma("unroll")                                                          \
    for (int mt = 0; mt < 4; ++mt)                                             \
        _Pragma("unroll")                                                      \
        for (int nt = 0; nt < 2; ++nt)                                         \
            acc[mt][nt] = __builtin_amdgcn_mfma_f32_32x32x16_bf16(a0_[mt], b0_[nt], acc[mt][nt], 0, 0, 0); \
    _Pragma("unroll")                                                          \
    for (int mt = 0; mt < 4; ++mt)                                             \
        _Pragma("unroll")                                                      \
        for (int nt = 0; nt < 2; ++nt)                                         \
            acc[mt][nt] = __builtin_amdgcn_mfma_f32_32x32x16_bf16(a1_[mt], b1_[nt], acc[mt][nt], 0, 0, 0); \
    __builtin_amdgcn_s_setprio(0);                                             \
} while (0)

    // prologue: stage K-tiles 0,1,2 (12 loads/thread); wait tile 0 (8 in flight)
    STAGE4(0);
    STAGE4(1);
    STAGE4(2);
    asm volatile("s_waitcnt vmcnt(8)" ::: "memory");
    __builtin_amdgcn_s_barrier();
    asm volatile("" ::: "memory");

    // main loop: stage kt+3, compute kt, wait kt+1's loads (vmcnt 12->8), barrier
    for (int kt = 0; kt < 21; ++kt) {
        STAGE4(kt + 3);
        KBODY((kt & 3) * 16384);
        asm volatile("s_waitcnt vmcnt(8)" ::: "memory");
        __builtin_amdgcn_s_barrier();
        asm volatile("" ::: "memory");
    }
    // drain: tiles 21, 22, 23
    KBODY(1 * 16384);
    asm volatile("s_waitcnt vmcnt(4)" ::: "memory");
    __builtin_amdgcn_s_barrier();
    asm volatile("" ::: "memory");
    KBODY(2 * 16384);
    asm volatile("s_waitcnt vmcnt(0)" ::: "memory");
    __builtin_amdgcn_s_barrier();
    asm volatile("" ::: "memory");
    KBODY(3 * 16384);

    // ---- top-2 screen epilogue (s-space: dv = -acc, smaller = better) ----
    // C/D map (verified): col = lane&31, row = (reg&3)+8*(reg>>2)+4*(lane>>5)
    float v1[2], v2[2];
    int k1[2];
#pragma unroll
    for (int nt = 0; nt < 2; ++nt) { v1[nt] = 3.4e38f; v2[nt] = 3.4e38f; k1[nt] = 0; }
#pragma unroll
    for (int mt = 0; mt < 4; ++mt) {
#pragma unroll
        for (int r = 0; r < 16; ++r) {
            int code = kc0 + wm * 128 + mt * 32 + (r & 3) + 8 * (r >> 2) + 4 * lhi;
#pragma unroll
            for (int nt = 0; nt < 2; ++nt) {
                float dv = -acc[mt][nt][r];
                bool lt = dv < v1[nt];
                v2[nt] = fminf(v2[nt], fmaxf(v1[nt], dv));
                v1[nt] = fminf(v1[nt], dv);
                k1[nt] = lt ? code : k1[nt];
            }
        }
    }
    // lanes l and l^32 cover rows offset 0/4 of the same col: one xor-32 merge
#pragma unroll
    for (int nt = 0; nt < 2; ++nt) {
        float ov1 = __shfl_xor(v1[nt], 32, 64);
        float ov2 = __shfl_xor(v2[nt], 32, 64);
        int ok1 = __shfl_xor(k1[nt], 32, 64);
        bool take = (ov1 < v1[nt]) || (ov1 == v1[nt] && ok1 < k1[nt]);
        if (take) { v2[nt] = fminf(v1[nt], ov2); v1[nt] = ov1; k1[nt] = ok1; }
        else v2[nt] = fminf(v2[nt], ov1);
    }
    __syncthreads();  // pipeline fully done; reuse LDS for cross-wave merge
    float* sv1 = (float*)sAB;            // [256][2]
    float* sv2 = sv1 + 512;              // [256][2]
    int* sk1 = (int*)(sv2 + 512);        // [256][2]
    if (lhi == 0) {
#pragma unroll
        for (int nt = 0; nt < 2; ++nt) {
            int col = wn * 64 + nt * 32 + l31;
            sv1[col * 2 + wm] = v1[nt];
            sv2[col * 2 + wm] = v2[nt];
            sk1[col * 2 + wm] = k1[nt];
        }
    }
    __syncthreads();
    if (t < 256) {
        float a1 = sv1[t * 2], b1 = sv1[t * 2 + 1];
        float a2 = sv2[t * 2], b2 = sv2[t * 2 + 1];
        int ak = sk1[t * 2], bk = sk1[t * 2 + 1];
        bool tb = (b1 < a1) || (b1 == a1 && bk < ak);
        float w1 = tb ? b1 : a1;
        int wk = tb ? bk : ak;
        float w2 = tb ? fminf(b2, a1) : fminf(a2, b1);
        pv1[blockIdx.y * NP + n0 + t] = w1;
        pv2[blockIdx.y * NP + n0 + t] = w2;
        pk1[blockIdx.y * NP + n0 + t] = wk;
    }
#undef STAGE4
#undef KBODY
}

// merge 32 partials per point; packed holds winner k (or ~0 sentinel for
// flagged rows, which rescore_par then atomicMin-fills with exact values)
__global__ __launch_bounds__(256) void merge_top2(
    const float* __restrict__ pv1, const float* __restrict__ pv2,
    const int* __restrict__ pk1, int* __restrict__ list, int* __restrict__ nflag,
    unsigned long long* __restrict__ packed) {
    int n = blockIdx.x * 256 + threadIdx.x;
    float gv1 = 3.4e38f, gv2 = 3.4e38f;
    int gk1 = 0;
#pragma unroll
    for (int ct = 0; ct < NPART; ++ct) {
        float v1 = pv1[ct * NP + n];
        if (v1 < gv1) {
            gv2 = fminf(gv1, pv2[ct * NP + n]);
            gv1 = v1;
            gk1 = pk1[ct * NP + n];
        } else {
            gv2 = fminf(gv2, v1);
        }
    }
    int f = (gv2 - gv1 < MARGIN_S) ? 1 : 0;
    packed[n] = f ? 0xFFFFFFFFFFFFFFFFull : (unsigned long long)(unsigned)gk1;
    if (f) {
        int pos = atomicAdd(nflag, 1);
        list[pos] = n;
    }
}

// exact fp32 rescore of flagged rows, wave-cooperative (lanes along D).
// zq computed in-wave (f64) — constant per row, rank-neutral.
__global__ __launch_bounds__(256) void rescore_par(
    const float* __restrict__ z, const float* __restrict__ cb,
    const float* __restrict__ nrm, const float* __restrict__ wsq,
    const int* __restrict__ list, const int* __restrict__ nflag,
    unsigned long long* __restrict__ packed) {
    __shared__ float sz[256];
    int nf = *nflag;
    int t = threadIdx.x;
    int lane = t & 63, wv = t >> 6;
    for (int ii = blockIdx.x; ii < nf; ii += 64) {
        int n = list[ii];
        int b = n >> 10, hw = n & 1023;
        __syncthreads();
        sz[t] = z[(b * DD + t) * 1024 + hw];
        __syncthreads();
        float4 zr = ((const float4*)sz)[lane];
        double zqd = (double)zr.x * zr.x + (double)zr.y * zr.y
                   + (double)zr.z * zr.z + (double)zr.w * zr.w;
#pragma unroll
        for (int off = 32; off; off >>= 1) zqd += __shfl_xor(zqd, off, 64);
        float zq = (float)zqd;
        unsigned long long best = 0xFFFFFFFFFFFFFFFFull;
        int kbase = blockIdx.y * 256 + wv * 64;
        for (int j = 0; j < 64; ++j) {
            int k = kbase + j;
            float4 cc = *(const float4*)&cb[(size_t)k * DD + lane * 4];
            float p = (zr.x * cc.x + zr.y * cc.y) + (zr.z * cc.z + zr.w * cc.w);
#pragma unroll
            for (int off = 32; off; off >>= 1) p += __shfl_xor(p, off, 64);
            float dot = p / nrm[k];
            float dv = (zq + wsq[k]) - 2.0f * dot;
            unsigned bits = __float_as_uint(dv);
            bits = (bits & 0x80000000u) ? ~bits : (bits | 0x80000000u);
            unsigned long long pk = ((unsigned long long)bits << 32) | (unsigned)k;
            best = best < pk ? best : pk;
        }
        if (lane == 0) atomicMin(packed + n, best);
    }
}

// z_q gather (w = cb/nrm, identical rounding to prep) + loss partials;
// the d==0 slice also emits idx output + histogram.
__global__ __launch_bounds__(256) void gather_loss(
    const float* __restrict__ z, const float* __restrict__ cb,
    const float* __restrict__ nrm, const unsigned long long* __restrict__ packed,
    float* __restrict__ out, double* __restrict__ lossp, int* __restrict__ hist) {
    __shared__ double lred[4];
    int t = threadIdx.x;
    int base = (blockIdx.x * 256 + t) * 16;
    double s = 0.0;
#pragma unroll
    for (int q = 0; q < 4; ++q) {
        int e = base + q * 4;
        int b = e >> 18, d = (e >> 10) & 255, hw = e & 1023;
        int n = (b << 10) + hw;
        float4 zv = *(const float4*)&z[e];
        float o[4];
        int ks[4];
#pragma unroll
        for (int j = 0; j < 4; ++j) {
            ks[j] = (int)(packed[n + j] & 0xFFFFFFFFull);
            o[j] = cb[ks[j] * DD + d] / nrm[ks[j]];
        }
        *(float4*)&out[e] = make_float4(o[0], o[1], o[2], o[3]);
        if (d == 0) {
#pragma unroll
            for (int j = 0; j < 4; ++j) {
                out[ZQ_ELEMS + n + j] = (float)ks[j];
                atomicAdd(&hist[ks[j]], 1);
            }
        }
        float d0 = o[0] - zv.x, d1 = o[1] - zv.y, d2 = o[2] - zv.z, d3 = o[3] - zv.w;
        s += (double)(d0 * d0) + (double)(d1 * d1) + (double)(d2 * d2) + (double)(d3 * d3);
    }
    s = waveReduceD(s);
    int lane = t & 63, wid = t >> 6;
    if (lane == 0) lred[wid] = s;
    __syncthreads();
    if (t == 0) lossp[blockIdx.x] = lred[0] + lred[1] + lred[2] + lred[3];
}

// single block: loss from 512 partials + perplexity from histogram
__global__ __launch_bounds__(256) void finalize_kernel(
    const int* __restrict__ hist, const double* __restrict__ lossp,
    float* __restrict__ out) {
    __shared__ double lred[4];
    __shared__ double lsum;
    int t = threadIdx.x;
    int lane = t & 63, wid = t >> 6;
    double ls = lossp[t] + lossp[t + 256];
    ls = waveReduceD(ls);
    if (lane == 0) lred[wid] = ls;
    __syncthreads();
    if (t == 0) lsum = lred[0] + lred[1] + lred[2] + lred[3];
    __syncthreads();
    double s = 0.0;
    for (int i = t; i < KC; i += 256) {
        float p = (float)hist[i] * (1.0f / 8192.0f);
        float lg = logf(p + 1e-10f);
        s += (double)(p * lg);
    }
    s = waveReduceD(s);
    if (lane == 0) lred[wid] = s;
    __syncthreads();
    if (t == 0) {
        double tot = lred[0] + lred[1] + lred[2] + lred[3];
        float m = (float)(lsum / (double)ZQ_ELEMS);
        out[ZQ_ELEMS + NP] = m + 0.25f * m;
        out[ZQ_ELEMS + NP + 1] = expf(-(float)tot);
    }
}

extern "C" void kernel_launch(void* const* d_in, const int* in_sizes, int n_in,
                              void* d_out, int out_size, void* d_ws, size_t ws_size,
                              hipStream_t stream) {
    const float* z = (const float*)d_in[0];
    const float* cb = (const float*)d_in[1];
    float* out = (float*)d_out;
    char* ws = (char*)d_ws;

    unsigned short* Abig = (unsigned short*)(ws + OFF_ABIG);
    unsigned short* Bbig = (unsigned short*)(ws + OFF_BBIG);
    float* nrm = (float*)(ws + OFF_NRM);
    float* wsq = (float*)(ws + OFF_WSQ);
    float* pv1 = (float*)(ws + OFF_PV1);
    float* pv2 = (float*)(ws + OFF_PV2);
    int* pk1 = (int*)(ws + OFF_PK1);
    int* hist = (int*)(ws + OFF_HIST);
    double* lossp = (double*)(ws + OFF_LOSSP);
    unsigned long long* packed = (unsigned long long*)(ws + OFF_PACK);
    int* list = (int*)(ws + OFF_LIST);
    int* nflag = (int*)(ws + OFF_NFLG);

    prep<<<2 * KC, 256, 0, stream>>>(cb, z, Bbig, Abig, nrm, wsq, hist, nflag);
    gemm_top2<<<dim3(32, NPART), 512, 0, stream>>>(Abig, Bbig, wsq, pv1, pv2, pk1);
    merge_top2<<<NP / 256, 256, 0, stream>>>(pv1, pv2, pk1, list, nflag, packed);
    rescore_par<<<dim3(64, 32), 256, 0, stream>>>(z, cb, nrm, wsq, list, nflag, packed);
    gather_loss<<<ZQ_ELEMS / (256 * 16), 256, 0, stream>>>(z, cb, nrm, packed, out, lossp, hist);
    finalize_kernel<<<1, 256, 0, stream>>>(hist, lossp, out);
}

// Round 10
// 208.550 us; speedup vs baseline: 1.0866x; 1.0866x over previous
//
#include <hip/hip_runtime.h>
#include <hip/hip_bf16.h>
#include <math.h>

// VectorQuantizer: z [8,256,32,32] f32, codebook [8192,256] f32
// outputs (flat f32): z_q [2097152] NCHW, idx [8192] (as float), loss, perplexity
#define KC 8192
#define DD 256
#define NP 8192
#define ZQ_ELEMS 2097152
#define MARGIN_S 2.5e-4f   // s-space (== 5e-4 in d-space, validated rounds 4-8)
#define NPART 32           // code-group partials (gemm grid.y)

// ws layout (bytes)
#define OFF_ABIG 0u           // bf16 [8192][512]  (Zh | Zl)  points
#define OFF_BBIG 8388608u     // bf16 [8192][512]  (Wh | Wl)  codes
#define OFF_NRM  16777216u    // f32 [8192]
#define OFF_WSQ  16809984u    // f32 [8192]
#define OFF_PV1  16875520u    // f32 [32][8192]
#define OFF_PV2  17924096u    // f32 [32][8192]
#define OFF_PK1  18972672u    // i32 [32][8192]
#define OFF_LOSSP 20021248u   // f64 [512]
#define OFF_HIST 20090880u    // i32 [8192]
#define OFF_PACK 20123648u    // u64 [8192]
#define OFF_LIST 20189184u    // i32 [8192]
#define OFF_NFLG 20221952u    // i32 [1]

typedef __attribute__((ext_vector_type(8))) short bf16x8;
typedef __attribute__((ext_vector_type(4))) float f32x4;
typedef __attribute__((address_space(3))) void as3_void;
typedef const __attribute__((address_space(1))) void as1_cvoid;

#define GLOAD16(g, l) __builtin_amdgcn_global_load_lds((as1_cvoid*)(g), (as3_void*)(l), 16, 0, 0)

__device__ inline double waveReduceD(double v) {
#pragma unroll
    for (int off = 32; off; off >>= 1) v += __shfl_down(v, off, 64);
    return v;
}

static __device__ inline unsigned short f2bf(float f) {
    __hip_bfloat16 h = __float2bfloat16(f);  // RNE
    return *(unsigned short*)&h;
}
static __device__ inline float bf2f(unsigned short u) {
    unsigned v = ((unsigned)u) << 16;
    float f;
    __builtin_memcpy(&f, &v, 4);
    return f;
}

// fused prep:
//   blocks 0..8191: codebook rows (normalize + split + wsq/nrm + zero hist/nflag)
//   blocks 8192..8703: z tile-transpose (64d x 64hw per block, LDS-staged,
//                      coalesced reads AND writes) + bf16 hi/lo split
__global__ __launch_bounds__(256) void prep(
    const float* __restrict__ cb, const float* __restrict__ z,
    unsigned short* __restrict__ Bbig, unsigned short* __restrict__ Abig,
    float* __restrict__ nrm, float* __restrict__ wsq,
    int* __restrict__ hist, int* __restrict__ nflag) {
    __shared__ float tile[64][65];
    int bid = blockIdx.x, t = threadIdx.x;
    int lane = t & 63, wid = t >> 6;
    if (bid < KC) {
        __shared__ double lred[4];
        __shared__ float mh;
        int k = bid;
        if (k < 32) hist[k * 256 + t] = 0;
        if (k == 32 && t == 0) *nflag = 0;
        float c = cb[k * DD + t];
        double s = waveReduceD((double)c * (double)c);
        if (lane == 0) lred[wid] = s;
        __syncthreads();
        if (t == 0) {
            double tot = lred[0] + lred[1] + lred[2] + lred[3];
            float nf = sqrtf((float)tot);
            mh = fmaxf(nf, 1e-12f);
            nrm[k] = mh;
            wsq[k] = (float)(tot / ((double)mh * (double)mh));
        }
        __syncthreads();
        float wv = c / mh;
        unsigned short hi = f2bf(wv);
        unsigned short lo = f2bf(wv - bf2f(hi));
        Bbig[k * 512 + t] = hi;
        Bbig[k * 512 + 256 + t] = lo;
    } else {
        int zb = bid - KC;                 // 0..511
        int b = zb >> 6, ht = (zb >> 2) & 15, dt = zb & 3;
        int hw0 = ht * 64, d0 = dt * 64;
        // coalesced read: wave spans 64 consecutive hw for one d-row
#pragma unroll
        for (int i = 0; i < 16; ++i) {
            int dl = wid * 16 + i;
            tile[dl][lane] = z[(size_t)(b * DD + d0 + dl) * 1024 + hw0 + lane];
        }
        __syncthreads();
        // coalesced write: wave spans 64 consecutive d for one point row.
        // point row n = b*1024 + hw0 + nl needs z at (d = d0+lane, hw = hw0+nl)
        // == tile[lane][nl]  (column read; [64][65] pad -> conflict-free)
#pragma unroll
        for (int i = 0; i < 16; ++i) {
            int nl = wid * 16 + i;
            float v = tile[lane][nl];
            unsigned short hi = f2bf(v);
            unsigned short lo = f2bf(v - bf2f(hi));
            size_t base = (size_t)(b * 1024 + hw0 + nl) * 512 + d0 + lane;
            Abig[base] = hi;
            Abig[base + 256] = lo;
        }
    }
}

// Deep-pipelined MFMA GEMM + top-2 screen (R6 kernel, verified 110us/0-conflict).
// C[256 codes][256 points] per block; A = W (codes), B = Z (points).
// Quad-buffered LDS, stage depth 3, counted vmcnt(8) per K-tile, 1 barrier/K-tile.
// acc init = -wsq/2  =>  score dv = -acc = wsq/2 - dot (argmin == argmin d).
__global__ __launch_bounds__(512, 2) void gemm_top2(
    const unsigned short* __restrict__ Abig, const unsigned short* __restrict__ Bbig,
    const float* __restrict__ wsq,
    float* __restrict__ pv1, float* __restrict__ pv2, int* __restrict__ pk1) {
    // [buf 0..3][ W 256x32 (8192 sh) | Z 256x32 (8192 sh) ] = 128 KiB
    __shared__ unsigned short sAB[65536];

    int t = threadIdx.x;
    int l = t & 63, w = t >> 6;
    int wm = w >> 2, wn = w & 3;
    int kc0 = blockIdx.y * 256;   // code base (C rows)
    int n0 = blockIdx.x * 256;    // point base (C cols)

    // ---- staging geometry (chunk-XOR swizzle; proven 0-conflict) ----
    int row0 = t >> 2;            // rows 0..127 (j=0), +128 (j=1)
    int lsw = (((t & 3) ^ ((row0 >> 1) & 3)) << 3);  // inverse-swizzled src chunk (shorts)
    // frag-read swizzled sub-chunk (shorts)
    int subsw = (((l >> 4) ^ ((l >> 1) & 3)) << 3);

#define STAGE(kt_) do {                                                        \
    int p_ = (kt_) >> 3;                                                       \
    int zo_ = (p_ == 2 ? 256 : 0) + ((kt_) & 7) * 32;                          \
    int wo_ = (p_ == 1 ? 256 : 0) + ((kt_) & 7) * 32;                          \
    int b_ = ((kt_) & 3) * 16384;                                              \
    GLOAD16(Bbig + (size_t)(kc0 + row0) * 512 + wo_ + lsw, &sAB[b_ + t * 8]);  \
    GLOAD16(Bbig + (size_t)(kc0 + row0 + 128) * 512 + wo_ + lsw, &sAB[b_ + 4096 + t * 8]); \
    GLOAD16(Abig + (size_t)(n0 + row0) * 512 + zo_ + lsw, &sAB[b_ + 8192 + t * 8]); \
    GLOAD16(Abig + (size_t)(n0 + row0 + 128) * 512 + zo_ + lsw, &sAB[b_ + 12288 + t * 8]); \
} while (0)

    // accumulators: 8 m-frags (codes) x 4 n-frags (points); init = -wsq/2
    f32x4 acc[8][4];
#pragma unroll
    for (int mf = 0; mf < 8; ++mf) {
#pragma unroll
        for (int r = 0; r < 4; ++r) {
            float hv = -0.5f * wsq[kc0 + wm * 128 + mf * 16 + ((l >> 4) << 2) + r];
#pragma unroll
            for (int nf = 0; nf < 4; ++nf) acc[mf][nf][r] = hv;
        }
    }

#define KBODY(bufbase) do {                                                    \
    bf16x8 af[8], bfr[4];                                                      \
    _Pragma("unroll")                                                          \
    for (int mf = 0; mf < 8; ++mf)                                             \
        af[mf] = *(const bf16x8*)&sAB[(bufbase) + (wm * 128 + mf * 16 + (l & 15)) * 32 + subsw]; \
    _Pragma("unroll")                                                          \
    for (int nf = 0; nf < 4; ++nf)                                             \
        bfr[nf] = *(const bf16x8*)&sAB[(bufbase) + 8192 + (wn * 64 + nf * 16 + (l & 15)) * 32 + subsw]; \
    __builtin_amdgcn_s_setprio(1);                                             \
    _Pragma("unroll")                                                          \
    for (int mf = 0; mf < 8; ++mf)                                             \
        _Pragma("unroll")                                                      \
        for (int nf = 0; nf < 4; ++nf)                                         \
            acc[mf][nf] = __builtin_amdgcn_mfma_f32_16x16x32_bf16(af[mf], bfr[nf], acc[mf][nf], 0, 0, 0); \
    __builtin_amdgcn_s_setprio(0);                                             \
} while (0)

    // prologue: stage K-tiles 0,1,2 (12 loads/thread); wait tile 0 (8 in flight)
    STAGE(0);
    STAGE(1);
    STAGE(2);
    asm volatile("s_waitcnt vmcnt(8)" ::: "memory");
    __builtin_amdgcn_s_barrier();
    asm volatile("" ::: "memory");

    // main loop: stage kt+3, compute kt, wait kt+1's loads (vmcnt 12->8), barrier
    for (int kt = 0; kt < 21; ++kt) {
        STAGE(kt + 3);
        KBODY((kt & 3) * 16384);
        asm volatile("s_waitcnt vmcnt(8)" ::: "memory");
        __builtin_amdgcn_s_barrier();
        asm volatile("" ::: "memory");
    }
    // epilogue drain: kt = 21, 22, 23
    KBODY(1 * 16384);
    asm volatile("s_waitcnt vmcnt(4)" ::: "memory");
    __builtin_amdgcn_s_barrier();
    asm volatile("" ::: "memory");
    KBODY(2 * 16384);
    asm volatile("s_waitcnt vmcnt(0)" ::: "memory");
    __builtin_amdgcn_s_barrier();
    asm volatile("" ::: "memory");
    KBODY(3 * 16384);

    // ---- top-2 screen epilogue (s-space: dv = -acc, smaller = better) ----
    float v1[4], v2[4];
    int k1[4];
#pragma unroll
    for (int nf = 0; nf < 4; ++nf) { v1[nf] = 3.4e38f; v2[nf] = 3.4e38f; k1[nf] = 0; }
#pragma unroll
    for (int mf = 0; mf < 8; ++mf) {
#pragma unroll
        for (int r = 0; r < 4; ++r) {
            int code = kc0 + wm * 128 + mf * 16 + ((l >> 4) << 2) + r;
#pragma unroll
            for (int nf = 0; nf < 4; ++nf) {
                float dv = -acc[mf][nf][r];
                bool lt = dv < v1[nf];
                v2[nf] = fminf(v2[nf], fmaxf(v1[nf], dv));
                v1[nf] = fminf(v1[nf], dv);
                k1[nf] = lt ? code : k1[nf];
            }
        }
    }
    // merge across the 4 row-groups (lanes l, l^16, l^32, l^48 share cols)
#pragma unroll
    for (int nf = 0; nf < 4; ++nf) {
#pragma unroll
        for (int mask = 16; mask <= 32; mask <<= 1) {
            float ov1 = __shfl_xor(v1[nf], mask, 64);
            float ov2 = __shfl_xor(v2[nf], mask, 64);
            int ok1 = __shfl_xor(k1[nf], mask, 64);
            bool take = (ov1 < v1[nf]) || (ov1 == v1[nf] && ok1 < k1[nf]);
            if (take) { v2[nf] = fminf(v1[nf], ov2); v1[nf] = ov1; k1[nf] = ok1; }
            else v2[nf] = fminf(v2[nf], ov1);
        }
    }
    __syncthreads();  // pipeline fully done; reuse LDS for cross-wave merge
    float* sv1 = (float*)sAB;            // [256][2]
    float* sv2 = sv1 + 512;              // [256][2]
    int* sk1 = (int*)(sv2 + 512);        // [256][2]
    if ((l >> 4) == 0) {
#pragma unroll
        for (int nf = 0; nf < 4; ++nf) {
            int col = wn * 64 + nf * 16 + l;
            sv1[col * 2 + wm] = v1[nf];
            sv2[col * 2 + wm] = v2[nf];
            sk1[col * 2 + wm] = k1[nf];
        }
    }
    __syncthreads();
    if (t < 256) {
        float a1 = sv1[t * 2], b1 = sv1[t * 2 + 1];
        float a2 = sv2[t * 2], b2 = sv2[t * 2 + 1];
        int ak = sk1[t * 2], bk = sk1[t * 2 + 1];
        bool tb = (b1 < a1) || (b1 == a1 && bk < ak);
        float w1 = tb ? b1 : a1;
        int wk = tb ? bk : ak;
        float w2 = tb ? fminf(b2, a1) : fminf(a2, b1);
        pv1[blockIdx.y * NP + n0 + t] = w1;
        pv2[blockIdx.y * NP + n0 + t] = w2;
        pk1[blockIdx.y * NP + n0 + t] = wk;
    }
#undef STAGE
#undef KBODY
}

// merge 32 partials per point; packed holds winner k (or ~0 sentinel for
// flagged rows, which rescore_par then atomicMin-fills with exact values)
__global__ __launch_bounds__(256) void merge_top2(
    const float* __restrict__ pv1, const float* __restrict__ pv2,
    const int* __restrict__ pk1, int* __restrict__ list, int* __restrict__ nflag,
    unsigned long long* __restrict__ packed) {
    int n = blockIdx.x * 256 + threadIdx.x;
    float gv1 = 3.4e38f, gv2 = 3.4e38f;
    int gk1 = 0;
#pragma unroll
    for (int ct = 0; ct < NPART; ++ct) {
        float v1 = pv1[ct * NP + n];
        if (v1 < gv1) {
            gv2 = fminf(gv1, pv2[ct * NP + n]);
            gv1 = v1;
            gk1 = pk1[ct * NP + n];
        } else {
            gv2 = fminf(gv2, v1);
        }
    }
    int f = (gv2 - gv1 < MARGIN_S) ? 1 : 0;
    packed[n] = f ? 0xFFFFFFFFFFFFFFFFull : (unsigned long long)(unsigned)gk1;
    if (f) {
        int pos = atomicAdd(nflag, 1);
        list[pos] = n;
    }
}

// exact fp32 rescore of flagged rows, wave-cooperative (lanes along D).
// zq computed in-wave (f64) — constant per row, rank-neutral.
__global__ __launch_bounds__(256) void rescore_par(
    const float* __restrict__ z, const float* __restrict__ cb,
    const float* __restrict__ nrm, const float* __restrict__ wsq,
    const int* __restrict__ list, const int* __restrict__ nflag,
    unsigned long long* __restrict__ packed) {
    __shared__ float sz[256];
    int nf = *nflag;
    int t = threadIdx.x;
    int lane = t & 63, wv = t >> 6;
    for (int ii = blockIdx.x; ii < nf; ii += 64) {
        int n = list[ii];
        int b = n >> 10, hw = n & 1023;
        __syncthreads();
        sz[t] = z[(b * DD + t) * 1024 + hw];
        __syncthreads();
        float4 zr = ((const float4*)sz)[lane];
        double zqd = (double)zr.x * zr.x + (double)zr.y * zr.y
                   + (double)zr.z * zr.z + (double)zr.w * zr.w;
#pragma unroll
        for (int off = 32; off; off >>= 1) zqd += __shfl_xor(zqd, off, 64);
        float zq = (float)zqd;
        unsigned long long best = 0xFFFFFFFFFFFFFFFFull;
        int kbase = blockIdx.y * 256 + wv * 64;
        for (int j = 0; j < 64; ++j) {
            int k = kbase + j;
            float4 cc = *(const float4*)&cb[(size_t)k * DD + lane * 4];
            float p = (zr.x * cc.x + zr.y * cc.y) + (zr.z * cc.z + zr.w * cc.w);
#pragma unroll
            for (int off = 32; off; off >>= 1) p += __shfl_xor(p, off, 64);
            float dot = p / nrm[k];
            float dv = (zq + wsq[k]) - 2.0f * dot;
            unsigned bits = __float_as_uint(dv);
            bits = (bits & 0x80000000u) ? ~bits : (bits | 0x80000000u);
            unsigned long long pk = ((unsigned long long)bits << 32) | (unsigned)k;
            best = best < pk ? best : pk;
        }
        if (lane == 0) atomicMin(packed + n, best);
    }
}

// z_q gather (w = cb/nrm, identical rounding to prep) + loss partials;
// the d==0 slice also emits idx output + histogram.
__global__ __launch_bounds__(256) void gather_loss(
    const float* __restrict__ z, const float* __restrict__ cb,
    const float* __restrict__ nrm, const unsigned long long* __restrict__ packed,
    float* __restrict__ out, double* __restrict__ lossp, int* __restrict__ hist) {
    __shared__ double lred[4];
    int t = threadIdx.x;
    int base = (blockIdx.x * 256 + t) * 16;
    double s = 0.0;
#pragma unroll
    for (int q = 0; q < 4; ++q) {
        int e = base + q * 4;
        int b = e >> 18, d = (e >> 10) & 255, hw = e & 1023;
        int n = (b << 10) + hw;
        float4 zv = *(const float4*)&z[e];
        float o[4];
        int ks[4];
#pragma unroll
        for (int j = 0; j < 4; ++j) {
            ks[j] = (int)(packed[n + j] & 0xFFFFFFFFull);
            o[j] = cb[ks[j] * DD + d] / nrm[ks[j]];
        }
        *(float4*)&out[e] = make_float4(o[0], o[1], o[2], o[3]);
        if (d == 0) {
#pragma unroll
            for (int j = 0; j < 4; ++j) {
                out[ZQ_ELEMS + n + j] = (float)ks[j];
                atomicAdd(&hist[ks[j]], 1);
            }
        }
        float d0 = o[0] - zv.x, d1 = o[1] - zv.y, d2 = o[2] - zv.z, d3 = o[3] - zv.w;
        s += (double)(d0 * d0) + (double)(d1 * d1) + (double)(d2 * d2) + (double)(d3 * d3);
    }
    s = waveReduceD(s);
    int lane = t & 63, wid = t >> 6;
    if (lane == 0) lred[wid] = s;
    __syncthreads();
    if (t == 0) lossp[blockIdx.x] = lred[0] + lred[1] + lred[2] + lred[3];
}

// single block: loss from 512 partials + perplexity from histogram
__global__ __launch_bounds__(256) void finalize_kernel(
    const int* __restrict__ hist, const double* __restrict__ lossp,
    float* __restrict__ out) {
    __shared__ double lred[4];
    __shared__ double lsum;
    int t = threadIdx.x;
    int lane = t & 63, wid = t >> 6;
    double ls = lossp[t] + lossp[t + 256];
    ls = waveReduceD(ls);
    if (lane == 0) lred[wid] = ls;
    __syncthreads();
    if (t == 0) lsum = lred[0] + lred[1] + lred[2] + lred[3];
    __syncthreads();
    double s = 0.0;
    for (int i = t; i < KC; i += 256) {
        float p = (float)hist[i] * (1.0f / 8192.0f);
        float lg = logf(p + 1e-10f);
        s += (double)(p * lg);
    }
    s = waveReduceD(s);
    if (lane == 0) lred[wid] = s;
    __syncthreads();
    if (t == 0) {
        double tot = lred[0] + lred[1] + lred[2] + lred[3];
        float m = (float)(lsum / (double)ZQ_ELEMS);
        out[ZQ_ELEMS + NP] = m + 0.25f * m;
        out[ZQ_ELEMS + NP + 1] = expf(-(float)tot);
    }
}

extern "C" void kernel_launch(void* const* d_in, const int* in_sizes, int n_in,
                              void* d_out, int out_size, void* d_ws, size_t ws_size,
                              hipStream_t stream) {
    const float* z = (const float*)d_in[0];
    const float* cb = (const float*)d_in[1];
    float* out = (float*)d_out;
    char* ws = (char*)d_ws;

    unsigned short* Abig = (unsigned short*)(ws + OFF_ABIG);
    unsigned short* Bbig = (unsigned short*)(ws + OFF_BBIG);
    float* nrm = (float*)(ws + OFF_NRM);
    float* wsq = (float*)(ws + OFF_WSQ);
    float* pv1 = (float*)(ws + OFF_PV1);
    float* pv2 = (float*)(ws + OFF_PV2);
    int* pk1 = (int*)(ws + OFF_PK1);
    int* hist = (int*)(ws + OFF_HIST);
    double* lossp = (double*)(ws + OFF_LOSSP);
    unsigned long long* packed = (unsigned long long*)(ws + OFF_PACK);
    int* list = (int*)(ws + OFF_LIST);
    int* nflag = (int*)(ws + OFF_NFLG);

    prep<<<KC + 512, 256, 0, stream>>>(cb, z, Bbig, Abig, nrm, wsq, hist, nflag);
    gemm_top2<<<dim3(32, NPART), 512, 0, stream>>>(Abig, Bbig, wsq, pv1, pv2, pk1);
    merge_top2<<<NP / 256, 256, 0, stream>>>(pv1, pv2, pk1, list, nflag, packed);
    rescore_par<<<dim3(64, 32), 256, 0, stream>>>(z, cb, nrm, wsq, list, nflag, packed);
    gather_loss<<<ZQ_ELEMS / (256 * 16), 256, 0, stream>>>(z, cb, nrm, packed, out, lossp, hist);
    finalize_kernel<<<1, 256, 0, stream>>>(hist, lossp, out);
}

// Round 11
// 207.469 us; speedup vs baseline: 1.0923x; 1.0052x over previous
//
#include <hip/hip_runtime.h>
#include <hip/hip_bf16.h>
#include <math.h>

// VectorQuantizer: z [8,256,32,32] f32, codebook [8192,256] f32
// outputs (flat f32): z_q [2097152] NCHW, idx [8192] (as float), loss, perplexity
#define KC 8192
#define DD 256
#define NP 8192
#define ZQ_ELEMS 2097152
#define MARGIN_S 2.5e-4f   // s-space (== 5e-4 in d-space, validated rounds 4-10)
#define NPART 32           // code-group partials (gemm grid.y)

// ws layout (bytes)
#define OFF_ABIG 0u           // bf16 [8192][512]  (Zh | Zl)  points
#define OFF_BBIG 8388608u     // bf16 [8192][512]  (Wh | Wl)  codes
#define OFF_NRM  16777216u    // f32 [8192]
#define OFF_WSQ  16809984u    // f32 [8192]
#define OFF_PV1  16875520u    // f32 [32][8192]
#define OFF_PV2  17924096u    // f32 [32][8192]
#define OFF_PK1  18972672u    // i32 [32][8192]
#define OFF_LOSSP 20021248u   // f64 [512]
#define OFF_HIST 20090880u    // i32 [8192]
#define OFF_PACK 20123648u    // u64 [8192]
#define OFF_LIST 20189184u    // i32 [8192]
#define OFF_NFLG 20221952u    // i32 [1]

typedef __attribute__((ext_vector_type(8))) short bf16x8;
typedef __attribute__((ext_vector_type(4))) float f32x4;
typedef __attribute__((address_space(3))) void as3_void;
typedef const __attribute__((address_space(1))) void as1_cvoid;

#define GLOAD16(g, l) __builtin_amdgcn_global_load_lds((as1_cvoid*)(g), (as3_void*)(l), 16, 0, 0)

__device__ inline double waveReduceD(double v) {
#pragma unroll
    for (int off = 32; off; off >>= 1) v += __shfl_down(v, off, 64);
    return v;
}

static __device__ inline unsigned short f2bf(float f) {
    __hip_bfloat16 h = __float2bfloat16(f);  // RNE
    return *(unsigned short*)&h;
}
static __device__ inline float bf2f(unsigned short u) {
    unsigned v = ((unsigned)u) << 16;
    float f;
    __builtin_memcpy(&f, &v, 4);
    return f;
}

// fused prep:
//   blocks 0..8191: codebook rows (normalize + split + wsq/nrm + zero hist/nflag)
//   blocks 8192..8703: z tile-transpose (64d x 64hw per block, LDS-staged,
//                      coalesced reads AND writes) + bf16 hi/lo split
__global__ __launch_bounds__(256) void prep(
    const float* __restrict__ cb, const float* __restrict__ z,
    unsigned short* __restrict__ Bbig, unsigned short* __restrict__ Abig,
    float* __restrict__ nrm, float* __restrict__ wsq,
    int* __restrict__ hist, int* __restrict__ nflag) {
    __shared__ float tile[64][65];
    int bid = blockIdx.x, t = threadIdx.x;
    int lane = t & 63, wid = t >> 6;
    if (bid < KC) {
        __shared__ double lred[4];
        __shared__ float mh;
        int k = bid;
        if (k < 32) hist[k * 256 + t] = 0;
        if (k == 32 && t == 0) *nflag = 0;
        float c = cb[k * DD + t];
        double s = waveReduceD((double)c * (double)c);
        if (lane == 0) lred[wid] = s;
        __syncthreads();
        if (t == 0) {
            double tot = lred[0] + lred[1] + lred[2] + lred[3];
            float nf = sqrtf((float)tot);
            mh = fmaxf(nf, 1e-12f);
            nrm[k] = mh;
            wsq[k] = (float)(tot / ((double)mh * (double)mh));
        }
        __syncthreads();
        float wv = c / mh;
        unsigned short hi = f2bf(wv);
        unsigned short lo = f2bf(wv - bf2f(hi));
        Bbig[k * 512 + t] = hi;
        Bbig[k * 512 + 256 + t] = lo;
    } else {
        int zb = bid - KC;                 // 0..511
        int b = zb >> 6, ht = (zb >> 2) & 15, dt = zb & 3;
        int hw0 = ht * 64, d0 = dt * 64;
        // coalesced read: wave spans 64 consecutive hw for one d-row
#pragma unroll
        for (int i = 0; i < 16; ++i) {
            int dl = wid * 16 + i;
            tile[dl][lane] = z[(size_t)(b * DD + d0 + dl) * 1024 + hw0 + lane];
        }
        __syncthreads();
        // point row n = b*1024 + hw0 + nl needs z at (d = d0+lane, hw = hw0+nl)
        // == tile[lane][nl]  (column read; [64][65] pad -> conflict-free)
#pragma unroll
        for (int i = 0; i < 16; ++i) {
            int nl = wid * 16 + i;
            float v = tile[lane][nl];
            unsigned short hi = f2bf(v);
            unsigned short lo = f2bf(v - bf2f(hi));
            size_t base = (size_t)(b * 1024 + hw0 + nl) * 512 + d0 + lane;
            Abig[base] = hi;
            Abig[base + 256] = lo;
        }
    }
}

// Deep-pipelined MFMA GEMM + top-2 screen.
// R6 schedule (quad-buffer LDS, depth-3 staging, counted vmcnt, 1 barrier/tile)
// + REGISTER FRAGMENT PIPELINE: ds_read of tile kt+1's fragments issued BEFORE
// tile kt's MFMA cluster, so LDS latency hides under MFMA (two named frag sets,
// loop unrolled x2). C[256 codes][256 points]; A = W (codes), B = Z (points).
// acc init = -wsq/2  =>  score dv = -acc = wsq/2 - dot (argmin == argmin d).
__global__ __launch_bounds__(512, 2) void gemm_top2(
    const unsigned short* __restrict__ Abig, const unsigned short* __restrict__ Bbig,
    const float* __restrict__ wsq,
    float* __restrict__ pv1, float* __restrict__ pv2, int* __restrict__ pk1) {
    // [buf 0..3][ W 256x32 (8192 sh) | Z 256x32 (8192 sh) ] = 128 KiB
    __shared__ unsigned short sAB[65536];

    int t = threadIdx.x;
    int l = t & 63, w = t >> 6;
    int wm = w >> 2, wn = w & 3;
    int kc0 = blockIdx.y * 256;   // code base (C rows)
    int n0 = blockIdx.x * 256;    // point base (C cols)

    // ---- staging geometry (chunk-XOR swizzle; proven 0-conflict) ----
    int row0 = t >> 2;            // rows 0..127 (+128 second half)
    int lsw = (((t & 3) ^ ((row0 >> 1) & 3)) << 3);  // inverse-swizzled src chunk (shorts)
    int subsw = (((l >> 4) ^ ((l >> 1) & 3)) << 3);  // frag-read swizzled sub-chunk

#define STAGE(kt_) do {                                                        \
    int p_ = (kt_) >> 3;                                                       \
    int zo_ = (p_ == 2 ? 256 : 0) + ((kt_) & 7) * 32;                          \
    int wo_ = (p_ == 1 ? 256 : 0) + ((kt_) & 7) * 32;                          \
    int b_ = ((kt_) & 3) * 16384;                                              \
    GLOAD16(Bbig + (size_t)(kc0 + row0) * 512 + wo_ + lsw, &sAB[b_ + t * 8]);  \
    GLOAD16(Bbig + (size_t)(kc0 + row0 + 128) * 512 + wo_ + lsw, &sAB[b_ + 4096 + t * 8]); \
    GLOAD16(Abig + (size_t)(n0 + row0) * 512 + zo_ + lsw, &sAB[b_ + 8192 + t * 8]); \
    GLOAD16(Abig + (size_t)(n0 + row0 + 128) * 512 + zo_ + lsw, &sAB[b_ + 12288 + t * 8]); \
} while (0)

#define LDFRAG(bufbase, fa, fb) do {                                           \
    _Pragma("unroll")                                                          \
    for (int mf = 0; mf < 8; ++mf)                                             \
        fa[mf] = *(const bf16x8*)&sAB[(bufbase) + (wm * 128 + mf * 16 + (l & 15)) * 32 + subsw]; \
    _Pragma("unroll")                                                          \
    for (int nf = 0; nf < 4; ++nf)                                             \
        fb[nf] = *(const bf16x8*)&sAB[(bufbase) + 8192 + (wn * 64 + nf * 16 + (l & 15)) * 32 + subsw]; \
} while (0)

#define MFMACL(fa, fb) do {                                                    \
    __builtin_amdgcn_s_setprio(1);                                             \
    _Pragma("unroll")                                                          \
    for (int mf = 0; mf < 8; ++mf)                                             \
        _Pragma("unroll")                                                      \
        for (int nf = 0; nf < 4; ++nf)                                         \
            acc[mf][nf] = __builtin_amdgcn_mfma_f32_16x16x32_bf16(fa[mf], fb[nf], acc[mf][nf], 0, 0, 0); \
    __builtin_amdgcn_s_setprio(0);                                             \
} while (0)

#define WAITBAR(n_) do {                                                       \
    asm volatile("s_waitcnt vmcnt(" #n_ ")" ::: "memory");                     \
    __builtin_amdgcn_s_barrier();                                              \
    asm volatile("" ::: "memory");                                             \
} while (0)

    // accumulators: 8 m-frags (codes) x 4 n-frags (points); init = -wsq/2
    f32x4 acc[8][4];
#pragma unroll
    for (int mf = 0; mf < 8; ++mf) {
#pragma unroll
        for (int r = 0; r < 4; ++r) {
            float hv = -0.5f * wsq[kc0 + wm * 128 + mf * 16 + ((l >> 4) << 2) + r];
#pragma unroll
            for (int nf = 0; nf < 4; ++nf) acc[mf][nf][r] = hv;
        }
    }

    bf16x8 fa0[8], fb0[4], fa1[8], fb1[4];

    // prologue: stage tiles 0,1,2; tile 0 resident; preload its fragments
    STAGE(0);
    STAGE(1);
    STAGE(2);
    WAITBAR(8);
    LDFRAG(0, fa0, fb0);

    // main loop (unrolled x2): per tile = wait(next resident) -> barrier ->
    // prefetch next frags -> stage kt+3 -> MFMA current
    for (int kt = 0; kt < 20; kt += 2) {
        WAITBAR(4);                               // tile kt+1 resident
        LDFRAG(((kt + 1) & 3) * 16384, fa1, fb1);
        STAGE(kt + 3);
        MFMACL(fa0, fb0);                         // tile kt
        WAITBAR(4);                               // tile kt+2 resident
        LDFRAG(((kt + 2) & 3) * 16384, fa0, fb0);
        STAGE(kt + 4);
        MFMACL(fa1, fb1);                         // tile kt+1
    }
    // tiles 20..23 drain
    WAITBAR(4);                                   // tile 21 resident
    LDFRAG(1 * 16384, fa1, fb1);
    STAGE(23);
    MFMACL(fa0, fb0);                             // tile 20
    WAITBAR(4);                                   // tile 22 resident
    LDFRAG(2 * 16384, fa0, fb0);
    MFMACL(fa1, fb1);                             // tile 21
    WAITBAR(0);                                   // tile 23 resident
    LDFRAG(3 * 16384, fa1, fb1);
    MFMACL(fa0, fb0);                             // tile 22
    MFMACL(fa1, fb1);                             // tile 23

    // ---- top-2 screen epilogue (s-space: dv = -acc, smaller = better) ----
    float v1[4], v2[4];
    int k1[4];
#pragma unroll
    for (int nf = 0; nf < 4; ++nf) { v1[nf] = 3.4e38f; v2[nf] = 3.4e38f; k1[nf] = 0; }
#pragma unroll
    for (int mf = 0; mf < 8; ++mf) {
#pragma unroll
        for (int r = 0; r < 4; ++r) {
            int code = kc0 + wm * 128 + mf * 16 + ((l >> 4) << 2) + r;
#pragma unroll
            for (int nf = 0; nf < 4; ++nf) {
                float dv = -acc[mf][nf][r];
                bool lt = dv < v1[nf];
                v2[nf] = fminf(v2[nf], fmaxf(v1[nf], dv));
                v1[nf] = fminf(v1[nf], dv);
                k1[nf] = lt ? code : k1[nf];
            }
        }
    }
    // merge across the 4 row-groups (lanes l, l^16, l^32, l^48 share cols)
#pragma unroll
    for (int nf = 0; nf < 4; ++nf) {
#pragma unroll
        for (int mask = 16; mask <= 32; mask <<= 1) {
            float ov1 = __shfl_xor(v1[nf], mask, 64);
            float ov2 = __shfl_xor(v2[nf], mask, 64);
            int ok1 = __shfl_xor(k1[nf], mask, 64);
            bool take = (ov1 < v1[nf]) || (ov1 == v1[nf] && ok1 < k1[nf]);
            if (take) { v2[nf] = fminf(v1[nf], ov2); v1[nf] = ov1; k1[nf] = ok1; }
            else v2[nf] = fminf(v2[nf], ov1);
        }
    }
    __syncthreads();  // pipeline fully done; reuse LDS for cross-wave merge
    float* sv1 = (float*)sAB;            // [256][2]
    float* sv2 = sv1 + 512;              // [256][2]
    int* sk1 = (int*)(sv2 + 512);        // [256][2]
    if ((l >> 4) == 0) {
#pragma unroll
        for (int nf = 0; nf < 4; ++nf) {
            int col = wn * 64 + nf * 16 + l;
            sv1[col * 2 + wm] = v1[nf];
            sv2[col * 2 + wm] = v2[nf];
            sk1[col * 2 + wm] = k1[nf];
        }
    }
    __syncthreads();
    if (t < 256) {
        float a1 = sv1[t * 2], b1 = sv1[t * 2 + 1];
        float a2 = sv2[t * 2], b2 = sv2[t * 2 + 1];
        int ak = sk1[t * 2], bk = sk1[t * 2 + 1];
        bool tb = (b1 < a1) || (b1 == a1 && bk < ak);
        float w1 = tb ? b1 : a1;
        int wk = tb ? bk : ak;
        float w2 = tb ? fminf(b2, a1) : fminf(a2, b1);
        pv1[blockIdx.y * NP + n0 + t] = w1;
        pv2[blockIdx.y * NP + n0 + t] = w2;
        pk1[blockIdx.y * NP + n0 + t] = wk;
    }
#undef STAGE
#undef LDFRAG
#undef MFMACL
#undef WAITBAR
}

// merge 32 partials per point; packed holds winner k (or ~0 sentinel for
// flagged rows, which rescore_par then atomicMin-fills with exact values)
__global__ __launch_bounds__(256) void merge_top2(
    const float* __restrict__ pv1, const float* __restrict__ pv2,
    const int* __restrict__ pk1, int* __restrict__ list, int* __restrict__ nflag,
    unsigned long long* __restrict__ packed) {
    int n = blockIdx.x * 256 + threadIdx.x;
    float gv1 = 3.4e38f, gv2 = 3.4e38f;
    int gk1 = 0;
#pragma unroll
    for (int ct = 0; ct < NPART; ++ct) {
        float v1 = pv1[ct * NP + n];
        if (v1 < gv1) {
            gv2 = fminf(gv1, pv2[ct * NP + n]);
            gv1 = v1;
            gk1 = pk1[ct * NP + n];
        } else {
            gv2 = fminf(gv2, v1);
        }
    }
    int f = (gv2 - gv1 < MARGIN_S) ? 1 : 0;
    packed[n] = f ? 0xFFFFFFFFFFFFFFFFull : (unsigned long long)(unsigned)gk1;
    if (f) {
        int pos = atomicAdd(nflag, 1);
        list[pos] = n;
    }
}

// exact fp32 rescore of flagged rows, wave-cooperative (lanes along D).
// zq computed in-wave (f64) — constant per row, rank-neutral.
__global__ __launch_bounds__(256) void rescore_par(
    const float* __restrict__ z, const float* __restrict__ cb,
    const float* __restrict__ nrm, const float* __restrict__ wsq,
    const int* __restrict__ list, const int* __restrict__ nflag,
    unsigned long long* __restrict__ packed) {
    __shared__ float sz[256];
    int nf = *nflag;
    int t = threadIdx.x;
    int lane = t & 63, wv = t >> 6;
    for (int ii = blockIdx.x; ii < nf; ii += 64) {
        int n = list[ii];
        int b = n >> 10, hw = n & 1023;
        __syncthreads();
        sz[t] = z[(b * DD + t) * 1024 + hw];
        __syncthreads();
        float4 zr = ((const float4*)sz)[lane];
        double zqd = (double)zr.x * zr.x + (double)zr.y * zr.y
                   + (double)zr.z * zr.z + (double)zr.w * zr.w;
#pragma unroll
        for (int off = 32; off; off >>= 1) zqd += __shfl_xor(zqd, off, 64);
        float zq = (float)zqd;
        unsigned long long best = 0xFFFFFFFFFFFFFFFFull;
        int kbase = blockIdx.y * 256 + wv * 64;
        for (int j = 0; j < 64; ++j) {
            int k = kbase + j;
            float4 cc = *(const float4*)&cb[(size_t)k * DD + lane * 4];
            float p = (zr.x * cc.x + zr.y * cc.y) + (zr.z * cc.z + zr.w * cc.w);
#pragma unroll
            for (int off = 32; off; off >>= 1) p += __shfl_xor(p, off, 64);
            float dot = p / nrm[k];
            float dv = (zq + wsq[k]) - 2.0f * dot;
            unsigned bits = __float_as_uint(dv);
            bits = (bits & 0x80000000u) ? ~bits : (bits | 0x80000000u);
            unsigned long long pk = ((unsigned long long)bits << 32) | (unsigned)k;
            best = best < pk ? best : pk;
        }
        if (lane == 0) atomicMin(packed + n, best);
    }
}

// z_q gather (w = cb/nrm, identical rounding to prep) + loss partials;
// the d==0 slice also emits idx output + histogram.
__global__ __launch_bounds__(256) void gather_loss(
    const float* __restrict__ z, const float* __restrict__ cb,
    const float* __restrict__ nrm, const unsigned long long* __restrict__ packed,
    float* __restrict__ out, double* __restrict__ lossp, int* __restrict__ hist) {
    __shared__ double lred[4];
    int t = threadIdx.x;
    int base = (blockIdx.x * 256 + t) * 16;
    double s = 0.0;
#pragma unroll
    for (int q = 0; q < 4; ++q) {
        int e = base + q * 4;
        int b = e >> 18, d = (e >> 10) & 255, hw = e & 1023;
        int n = (b << 10) + hw;
        float4 zv = *(const float4*)&z[e];
        float o[4];
        int ks[4];
#pragma unroll
        for (int j = 0; j < 4; ++j) {
            ks[j] = (int)(packed[n + j] & 0xFFFFFFFFull);
            o[j] = cb[ks[j] * DD + d] / nrm[ks[j]];
        }
        *(float4*)&out[e] = make_float4(o[0], o[1], o[2], o[3]);
        if (d == 0) {
#pragma unroll
            for (int j = 0; j < 4; ++j) {
                out[ZQ_ELEMS + n + j] = (float)ks[j];
                atomicAdd(&hist[ks[j]], 1);
            }
        }
        float d0 = o[0] - zv.x, d1 = o[1] - zv.y, d2 = o[2] - zv.z, d3 = o[3] - zv.w;
        s += (double)(d0 * d0) + (double)(d1 * d1) + (double)(d2 * d2) + (double)(d3 * d3);
    }
    s = waveReduceD(s);
    int lane = t & 63, wid = t >> 6;
    if (lane == 0) lred[wid] = s;
    __syncthreads();
    if (t == 0) lossp[blockIdx.x] = lred[0] + lred[1] + lred[2] + lred[3];
}

// single block: loss from 512 partials + perplexity from histogram
__global__ __launch_bounds__(256) void finalize_kernel(
    const int* __restrict__ hist, const double* __restrict__ lossp,
    float* __restrict__ out) {
    __shared__ double lred[4];
    __shared__ double lsum;
    int t = threadIdx.x;
    int lane = t & 63, wid = t >> 6;
    double ls = lossp[t] + lossp[t + 256];
    ls = waveReduceD(ls);
    if (lane == 0) lred[wid] = ls;
    __syncthreads();
    if (t == 0) lsum = lred[0] + lred[1] + lred[2] + lred[3];
    __syncthreads();
    double s = 0.0;
    for (int i = t; i < KC; i += 256) {
        float p = (float)hist[i] * (1.0f / 8192.0f);
        float lg = logf(p + 1e-10f);
        s += (double)(p * lg);
    }
    s = waveReduceD(s);
    if (lane == 0) lred[wid] = s;
    __syncthreads();
    if (t == 0) {
        double tot = lred[0] + lred[1] + lred[2] + lred[3];
        float m = (float)(lsum / (double)ZQ_ELEMS);
        out[ZQ_ELEMS + NP] = m + 0.25f * m;
        out[ZQ_ELEMS + NP + 1] = expf(-(float)tot);
    }
}

extern "C" void kernel_launch(void* const* d_in, const int* in_sizes, int n_in,
                              void* d_out, int out_size, void* d_ws, size_t ws_size,
                              hipStream_t stream) {
    const float* z = (const float*)d_in[0];
    const float* cb = (const float*)d_in[1];
    float* out = (float*)d_out;
    char* ws = (char*)d_ws;

    unsigned short* Abig = (unsigned short*)(ws + OFF_ABIG);
    unsigned short* Bbig = (unsigned short*)(ws + OFF_BBIG);
    float* nrm = (float*)(ws + OFF_NRM);
    float* wsq = (float*)(ws + OFF_WSQ);
    float* pv1 = (float*)(ws + OFF_PV1);
    float* pv2 = (float*)(ws + OFF_PV2);
    int* pk1 = (int*)(ws + OFF_PK1);
    int* hist = (int*)(ws + OFF_HIST);
    double* lossp = (double*)(ws + OFF_LOSSP);
    unsigned long long* packed = (unsigned long long*)(ws + OFF_PACK);
    int* list = (int*)(ws + OFF_LIST);
    int* nflag = (int*)(ws + OFF_NFLG);

    prep<<<KC + 512, 256, 0, stream>>>(cb, z, Bbig, Abig, nrm, wsq, hist, nflag);
    gemm_top2<<<dim3(32, NPART), 512, 0, stream>>>(Abig, Bbig, wsq, pv1, pv2, pk1);
    merge_top2<<<NP / 256, 256, 0, stream>>>(pv1, pv2, pk1, list, nflag, packed);
    rescore_par<<<dim3(64, 32), 256, 0, stream>>>(z, cb, nrm, wsq, list, nflag, packed);
    gather_loss<<<ZQ_ELEMS / (256 * 16), 256, 0, stream>>>(z, cb, nrm, packed, out, lossp, hist);
    finalize_kernel<<<1, 256, 0, stream>>>(hist, lossp, out);
}